// Round 3
// baseline (391.913 us; speedup 1.0000x reference)
//
#include <hip/hip_runtime.h>
#include <hip/hip_bf16.h>
#include <math.h>

using bf16 = __hip_bfloat16;

static constexpr int Bn = 4;
static constexpr int Tn = 2048;
static constexpr int Dn = 1024;

typedef __attribute__((ext_vector_type(8))) short bf16x8;
typedef __attribute__((ext_vector_type(4))) float f32x4;

__device__ __forceinline__ float ldf(float v) { return v; }
__device__ __forceinline__ float ldf(bf16 v) { return __bfloat162float(v); }
__device__ __forceinline__ bf16 f2b(float v) { return __float2bfloat16(v); }
__device__ __forceinline__ float b2f(short s) {
    return __uint_as_float(((unsigned)(unsigned short)s) << 16);
}
__device__ __forceinline__ short f2bs(float v) {
    bf16 t = __float2bfloat16(v);
    return *reinterpret_cast<short*>(&t);
}

template <typename T> __device__ __forceinline__ T from_float(float v);
template <> __device__ __forceinline__ float from_float<float>(float v) { return v; }
template <> __device__ __forceinline__ bf16 from_float<bf16>(float v) { return f2b(v); }

__device__ __forceinline__ void load4(const float* p, float* v) {
    const float4 t = *(const float4*)p;
    v[0] = t.x; v[1] = t.y; v[2] = t.z; v[3] = t.w;
}
__device__ __forceinline__ void load4(const bf16* p, float* v) {
    const short4 t = *(const short4*)p;
    v[0] = b2f(t.x); v[1] = b2f(t.y); v[2] = b2f(t.z); v[3] = b2f(t.w);
}

// async global->LDS, 16B per lane; LDS dest wave-uniform base, HW scatters +lane*16.
__device__ __forceinline__ void async_copy16(const bf16* g, bf16* l) {
    __builtin_amdgcn_global_load_lds(
        (const __attribute__((address_space(1))) void*)g,
        (__attribute__((address_space(3))) void*)l,
        16, 0, 0);
}

// ---------------------------------------------------------------------------
// 8-phase 256x256 NT GEMM (bf16), BK=32, 3-deep ring, counted vmcnt(4).
// Proven in rounds 1-2 (QK). Unchanged.
// ---------------------------------------------------------------------------
__global__ __launch_bounds__(512, 2) void gemm8p(
    const bf16* __restrict__ A, const bf16* __restrict__ Bm,
    bf16* __restrict__ C, int K, int lda, int ldb, int ldc)
{
    constexpr int BM = 256, BN = 256, BK = 32;
    constexpr int BUFE = (BM + BN) * BK;
    __shared__ __align__(16) bf16 smem[3 * BUFE];

    const int bm = blockIdx.x, bn = blockIdx.y;
    const int tid = threadIdx.x;
    const int wave = tid >> 6;
    const int lane = tid & 63;
    const int wm = wave >> 2;
    const int wn = wave & 3;
    const int lr = lane >> 2;
    const int lc = (lane & 3) * 8;
    const int arow = lane & 15;
    const int kq = (lane >> 4) * 8;

    const int NK = K / BK;

    const bf16* gA0 = A + (size_t)(bm * BM + wave * 16 + lr) * lda + lc;
    const bf16* gA1 = A + (size_t)(bm * BM + (wave + 8) * 16 + lr) * lda + lc;
    const bf16* gB0 = Bm + (size_t)(bn * BN + wave * 16 + lr) * ldb + lc;
    const bf16* gB1 = Bm + (size_t)(bn * BN + (wave + 8) * 16 + lr) * ldb + lc;

    f32x4 acc[8][4] = {};

    {
        bf16* As0 = smem;
        bf16* Bs0 = smem + BM * BK;
        bf16* As1 = smem + BUFE;
        bf16* Bs1 = smem + BUFE + BM * BK;
        async_copy16(gA0, As0 + wave * 512);
        async_copy16(gA1, As0 + (wave + 8) * 512);
        async_copy16(gB0, Bs0 + wave * 512);
        async_copy16(gB1, Bs0 + (wave + 8) * 512);
        async_copy16(gA0 + BK, As1 + wave * 512);
        async_copy16(gA1 + BK, As1 + (wave + 8) * 512);
        async_copy16(gB0 + BK, Bs1 + wave * 512);
        async_copy16(gB1 + BK, Bs1 + (wave + 8) * 512);
    }
    asm volatile("s_waitcnt vmcnt(4)" ::: "memory");
    __builtin_amdgcn_s_barrier();

    int cb = 0, sb = 2;
    for (int kt = 0; kt < NK; ++kt) {
        const bf16* As = smem + cb * BUFE;
        const bf16* Bs = As + BM * BK;
        const bool st = (kt + 2) < NK;
        const int koff = (kt + 2) * BK;

        bf16x8 af[8], bf0[2];
#pragma unroll
        for (int mt = 0; mt < 8; ++mt)
            af[mt] = *(const bf16x8*)&As[(wm * 8 + mt) * 512 + arow * 32 + kq];
#pragma unroll
        for (int nt = 0; nt < 2; ++nt)
            bf0[nt] = *(const bf16x8*)&Bs[(wn * 4 + nt) * 512 + arow * 32 + kq];
        if (st) {
            bf16* Ad = smem + sb * BUFE;
            async_copy16(gA0 + koff, Ad + wave * 512);
            async_copy16(gA1 + koff, Ad + (wave + 8) * 512);
        }
        __builtin_amdgcn_s_barrier();
        asm volatile("s_waitcnt lgkmcnt(0)" ::: "memory");
        __builtin_amdgcn_sched_barrier(0);
        __builtin_amdgcn_s_setprio(1);
#pragma unroll
        for (int mt = 0; mt < 8; ++mt)
#pragma unroll
            for (int nt = 0; nt < 2; ++nt)
                acc[mt][nt] = __builtin_amdgcn_mfma_f32_16x16x32_bf16(
                    af[mt], bf0[nt], acc[mt][nt], 0, 0, 0);
        __builtin_amdgcn_s_setprio(0);
        __builtin_amdgcn_s_barrier();

        bf16x8 bf1[2];
#pragma unroll
        for (int nt = 0; nt < 2; ++nt)
            bf1[nt] = *(const bf16x8*)&Bs[(wn * 4 + 2 + nt) * 512 + arow * 32 + kq];
        if (st) {
            bf16* Bd = smem + sb * BUFE + BM * BK;
            async_copy16(gB0 + koff, Bd + wave * 512);
            async_copy16(gB1 + koff, Bd + (wave + 8) * 512);
        }
        __builtin_amdgcn_s_barrier();
        asm volatile("s_waitcnt lgkmcnt(0)" ::: "memory");
        __builtin_amdgcn_sched_barrier(0);
        __builtin_amdgcn_s_setprio(1);
#pragma unroll
        for (int mt = 0; mt < 8; ++mt)
#pragma unroll
            for (int nt = 0; nt < 2; ++nt)
                acc[mt][2 + nt] = __builtin_amdgcn_mfma_f32_16x16x32_bf16(
                    af[mt], bf1[nt], acc[mt][2 + nt], 0, 0, 0);
        __builtin_amdgcn_s_setprio(0);
        if (st) asm volatile("s_waitcnt vmcnt(4)" ::: "memory");
        else    asm volatile("s_waitcnt vmcnt(0)" ::: "memory");
        __builtin_amdgcn_s_barrier();

        cb = (cb + 1 == 3) ? 0 : cb + 1;
        sb = (sb + 1 == 3) ? 0 : sb + 1;
    }

    const int row0 = bm * BM + wm * 128;
    const int col0 = bn * BN + wn * 64;
    const int qrow = (lane >> 4) * 4;
    const int ccol = lane & 15;
#pragma unroll
    for (int mt = 0; mt < 8; ++mt)
#pragma unroll
        for (int nt = 0; nt < 4; ++nt) {
            const int cc = col0 + nt * 16 + ccol;
#pragma unroll
            for (int r = 0; r < 4; ++r) {
                const int rr = row0 + mt * 16 + qrow + r;
                C[(size_t)rr * ldc + cc] = f2b(acc[mt][nt][r]);
            }
        }
}

// ---------------------------------------------------------------------------
// gemm8k: 256x128 NT GEMM, BK=64 as two 32-k hh-subphases of 16 MFMA each —
// same per-phase shape (10 ds_read_b128 + 16 MFMA) as the proven gemm8p
// phase, half the tiles. 3-deep ring (144 KiB LDS), 6 loads/tile, counted
// vmcnt(6). 8 waves as 2(M)x4(N): per-wave 128x32 out, acc[8][2].
// MODE 0: none; 1: causal block-skip (scores); 2: K truncated at bm*BM+BM.
// EPI 0: plain (+bias/RELU/residual); 1: V-transpose into vtp[b][d][t];
//     2: masked exp scores + atomic rowsum; 3: divide by rowsum, + fp32 res.
// ---------------------------------------------------------------------------
template <int EPI, int MODE, typename OutT, typename ResT, bool RELU>
__global__ __launch_bounds__(512, 2) void gemm8k(
    const bf16* __restrict__ A, const bf16* __restrict__ Bm,
    OutT* __restrict__ C, const float* __restrict__ bias,
    const ResT* __restrict__ res, bf16* __restrict__ vtp,
    float* __restrict__ rowsum,
    int K, int lda, int ldb, int ldc, int ldr,
    long sA, long sB, long sC, long sR)
{
    constexpr int BM = 256, BN = 128;
    constexpr int AE = BM * 32;            // elems per A hh-half (8192)
    constexpr int BE = BN * 32;            // elems per B hh-half (4096)
    constexpr int BUFE = 2 * (AE + BE);    // 24576 elems = 48 KiB
    __shared__ __align__(16) bf16 smem[3 * BUFE];   // 144 KiB

    const int bm = blockIdx.x, bn = blockIdx.y, bz = blockIdx.z;
    if (MODE == 1 && bn * BN > bm * BM + (BM - 1)) return;
    const int kend = bm * BM + BM;
    const int kmax = (MODE == 2) ? (kend < K ? kend : K) : K;
    const int NK = kmax >> 6;

    const bf16* Ab = A + (size_t)bz * sA;
    const bf16* Bb = Bm + (size_t)bz * sB;

    const int tid = threadIdx.x;
    const int wave = tid >> 6;
    const int lane = tid & 63;
    const int wm = wave >> 2;          // 0..1 (128 rows)
    const int wn = wave & 3;           // 0..3 (32 cols)
    const int lr = lane >> 2;
    const int lc = (lane & 3) * 8;
    const int arow = lane & 15;
    const int kq = (lane >> 4) * 8;

    const bf16* gA0 = Ab + (size_t)(bm * BM + wave * 16 + lr) * lda + lc;
    const bf16* gA1 = Ab + (size_t)(bm * BM + (wave + 8) * 16 + lr) * lda + lc;
    const bf16* gB0 = Bb + (size_t)(bn * BN + wave * 16 + lr) * ldb + lc;

    f32x4 acc[8][2] = {};

    auto stageA = [&](bf16* buf, int k0) {
        async_copy16(gA0 + k0,      buf + wave * 512);
        async_copy16(gA1 + k0,      buf + (wave + 8) * 512);
        async_copy16(gA0 + k0 + 32, buf + AE + wave * 512);
        async_copy16(gA1 + k0 + 32, buf + AE + (wave + 8) * 512);
    };
    auto stageB = [&](bf16* buf, int k0) {
        async_copy16(gB0 + k0,      buf + 2 * AE + wave * 512);
        async_copy16(gB0 + k0 + 32, buf + 2 * AE + BE + wave * 512);
    };

    // prologue: stage tiles 0,1 (6 loads each); wait tile 0 -> vmcnt(6)
    stageA(smem, 0);        stageB(smem, 0);
    stageA(smem + BUFE, 64); stageB(smem + BUFE, 64);
    asm volatile("s_waitcnt vmcnt(6)" ::: "memory");
    __builtin_amdgcn_s_barrier();

    int cb = 0, sb = 2;
    for (int kt = 0; kt < NK; ++kt) {
        const bf16* As = smem + cb * BUFE;
        const bf16* Bs = As + 2 * AE;
        const bool st = (kt + 2) < NK;
        const int koff = (kt + 2) * 64;

        // ---- subphase hh=0 ----
        bf16x8 af[8], bfr[2];
#pragma unroll
        for (int mt = 0; mt < 8; ++mt)
            af[mt] = *(const bf16x8*)&As[(wm * 8 + mt) * 512 + arow * 32 + kq];
#pragma unroll
        for (int nt = 0; nt < 2; ++nt)
            bfr[nt] = *(const bf16x8*)&Bs[(wn * 2 + nt) * 512 + arow * 32 + kq];
        if (st) stageA(smem + sb * BUFE, koff);
        __builtin_amdgcn_s_barrier();
        asm volatile("s_waitcnt lgkmcnt(0)" ::: "memory");
        __builtin_amdgcn_sched_barrier(0);
        __builtin_amdgcn_s_setprio(1);
#pragma unroll
        for (int mt = 0; mt < 8; ++mt)
#pragma unroll
            for (int nt = 0; nt < 2; ++nt)
                acc[mt][nt] = __builtin_amdgcn_mfma_f32_16x16x32_bf16(
                    af[mt], bfr[nt], acc[mt][nt], 0, 0, 0);
        __builtin_amdgcn_s_setprio(0);
        __builtin_amdgcn_s_barrier();

        // ---- subphase hh=1 ----
        bf16x8 af2[8], bfr2[2];
#pragma unroll
        for (int mt = 0; mt < 8; ++mt)
            af2[mt] = *(const bf16x8*)&As[AE + (wm * 8 + mt) * 512 + arow * 32 + kq];
#pragma unroll
        for (int nt = 0; nt < 2; ++nt)
            bfr2[nt] = *(const bf16x8*)&Bs[BE + (wn * 2 + nt) * 512 + arow * 32 + kq];
        if (st) stageB(smem + sb * BUFE, koff);
        __builtin_amdgcn_s_barrier();
        asm volatile("s_waitcnt lgkmcnt(0)" ::: "memory");
        __builtin_amdgcn_sched_barrier(0);
        __builtin_amdgcn_s_setprio(1);
#pragma unroll
        for (int mt = 0; mt < 8; ++mt)
#pragma unroll
            for (int nt = 0; nt < 2; ++nt)
                acc[mt][nt] = __builtin_amdgcn_mfma_f32_16x16x32_bf16(
                    af2[mt], bfr2[nt], acc[mt][nt], 0, 0, 0);
        __builtin_amdgcn_s_setprio(0);
        if (st) asm volatile("s_waitcnt vmcnt(6)" ::: "memory");
        else    asm volatile("s_waitcnt vmcnt(0)" ::: "memory");
        __builtin_amdgcn_s_barrier();

        cb = (cb + 1 == 3) ? 0 : cb + 1;
        sb = (sb + 1 == 3) ? 0 : sb + 1;
    }

    const int qrow = (lane >> 4) * 4;
    const int ccol = lane & 15;
    const int row0 = bm * BM + wm * 128;
    const int col0 = bn * BN + wn * 32;

    if constexpr (EPI == 1) {
        // V-transpose: block out = 256(t) x 128(d); write vtp[b][d][t].
        bf16* tt = smem;   // safe: loop ended with barrier, all LDS ops drained
#pragma unroll
        for (int mt = 0; mt < 8; ++mt)
#pragma unroll
            for (int nt = 0; nt < 2; ++nt) {
                const int dl = wn * 32 + nt * 16 + ccol;
                const int tl = wm * 128 + mt * 16 + qrow;
                short4 o;
                o.x = f2bs(acc[mt][nt][0]);
                o.y = f2bs(acc[mt][nt][1]);
                o.z = f2bs(acc[mt][nt][2]);
                o.w = f2bs(acc[mt][nt][3]);
                *(short4*)&tt[dl * 264 + tl] = o;
            }
        __syncthreads();
        const int b = (bm * BM) >> 11;
        const int tin = (bm * BM) & (Tn - 1);
        const int dr = tid >> 4;           // 0..31
        const int t0 = (tid & 15) * 16;    // 0..240
#pragma unroll
        for (int p = 0; p < 4; ++p) {
            const int d = p * 32 + dr;
            const bf16* srcl = &tt[d * 264 + t0];
            bf16* dst = vtp + ((size_t)b * Dn + bn * BN + d) * Tn + tin + t0;
            ((bf16x8*)dst)[0] = ((const bf16x8*)srcl)[0];
            ((bf16x8*)dst)[1] = ((const bf16x8*)srcl)[1];
        }
        return;
    }

    if constexpr (EPI == 2) {
        // masked exp scores + atomic row sums (of the bf16-rounded values)
        OutT* Cb = C + (size_t)bz * sC;
        float* rsb = rowsum + (size_t)bz * Tn;
        const float scale = 0.03125f;
#pragma unroll
        for (int mt = 0; mt < 8; ++mt) {
            float rsv[4] = {0.f, 0.f, 0.f, 0.f};
#pragma unroll
            for (int nt = 0; nt < 2; ++nt) {
                const int cc = col0 + nt * 16 + ccol;
#pragma unroll
                for (int r = 0; r < 4; ++r) {
                    const int rr = row0 + mt * 16 + qrow + r;
                    float e = 0.0f;
                    if (cc <= rr) {
                        const short es = f2bs(__expf(acc[mt][nt][r] * scale));
                        Cb[(size_t)rr * ldc + cc] = *(const bf16*)&es;
                        e = b2f(es);
                    } else {
                        Cb[(size_t)rr * ldc + cc] = from_float<OutT>(0.0f);
                    }
                    rsv[r] += e;
                }
            }
#pragma unroll
            for (int r = 0; r < 4; ++r) {
                float v = rsv[r];
                v += __shfl_xor(v, 1);
                v += __shfl_xor(v, 2);
                v += __shfl_xor(v, 4);
                v += __shfl_xor(v, 8);
                if (ccol == 0)
                    atomicAdd(rsb + row0 + mt * 16 + qrow + r, v);
            }
        }
        return;
    }

    OutT* Cb = C + (size_t)bz * sC;
    const ResT* Rb = res ? (res + (size_t)bz * sR) : nullptr;
    const float* rsb = (EPI == 3) ? (rowsum + (size_t)bz * Tn) : nullptr;
#pragma unroll
    for (int mt = 0; mt < 8; ++mt) {
        float inv4[4];
        if constexpr (EPI == 3) {
#pragma unroll
            for (int r = 0; r < 4; ++r)
                inv4[r] = 1.0f / rsb[row0 + mt * 16 + qrow + r];
        }
#pragma unroll
        for (int nt = 0; nt < 2; ++nt) {
            const int cc = col0 + nt * 16 + ccol;
            const float bv = bias ? bias[cc] : 0.0f;
#pragma unroll
            for (int r = 0; r < 4; ++r) {
                const int rr = row0 + mt * 16 + qrow + r;
                float v = acc[mt][nt][r];
                if constexpr (EPI == 3) v *= inv4[r];
                v += bv;
                if (RELU) v = fmaxf(v, 0.0f);
                if (Rb) v += ldf(Rb[(size_t)rr * ldr + cc]);
                Cb[(size_t)rr * ldc + cc] = from_float<OutT>(v);
            }
        }
    }
}

// ---------------------------------------------------------------------------
// LayerNorm body (faithfully buggy): out = (x - mean/sqrt(var_unbiased))*g + b
// ---------------------------------------------------------------------------
template <typename InT>
__device__ __forceinline__ void ln_row(
    const InT* __restrict__ xr, const float* __restrict__ gamma,
    const float* __restrict__ beta, bf16* __restrict__ orow, int tid)
{
    const int j = tid * 4;
    float v[4];
    load4(xr + j, v);
    float s = v[0] + v[1] + v[2] + v[3];
    float sq = v[0] * v[0] + v[1] * v[1] + v[2] * v[2] + v[3] * v[3];
#pragma unroll
    for (int o = 32; o > 0; o >>= 1) {
        s += __shfl_down(s, o);
        sq += __shfl_down(sq, o);
    }
    __shared__ float red[2][4];
    const int lane = tid & 63, w = tid >> 6;
    if (lane == 0) { red[0][w] = s; red[1][w] = sq; }
    __syncthreads();
    s  = red[0][0] + red[0][1] + red[0][2] + red[0][3];
    sq = red[1][0] + red[1][1] + red[1][2] + red[1][3];
    const float mean = s / (float)Dn;
    const float var = (sq - s * s / (float)Dn) / (float)(Dn - 1);
    const float coef = mean * rsqrtf(var);

    const float4 g = *(const float4*)(gamma + j);
    const float4 be = *(const float4*)(beta + j);
    short4 o;
    o.x = f2bs((v[0] - coef) * g.x + be.x);
    o.y = f2bs((v[1] - coef) * g.y + be.y);
    o.z = f2bs((v[2] - coef) * g.z + be.z);
    o.w = f2bs((v[3] - coef) * g.w + be.w);
    *(short4*)(orow + j) = o;
}

template <typename InT>
__global__ __launch_bounds__(256) void ln_kernel(
    const InT* __restrict__ x, const float* __restrict__ gamma,
    const float* __restrict__ beta, bf16* __restrict__ out)
{
    const int row = blockIdx.x;
    ln_row(x + (size_t)row * Dn, gamma, beta, out + (size_t)row * Dn, threadIdx.x);
}

// ---------------------------------------------------------------------------
// Fused prep: [0,5120) weight transposes (5 x 1024^2, fp32->bf16),
// [5120,5128) zero rowsum, [5128,13320) LN1 rows.
// ---------------------------------------------------------------------------
struct WPtrs { const float* p[5]; };

__global__ __launch_bounds__(256) void prep_kernel(
    WPtrs wp, bf16* __restrict__ wdst, float* __restrict__ rowsum,
    const float* __restrict__ x, const float* __restrict__ gamma1,
    const float* __restrict__ beta1, bf16* __restrict__ h)
{
    const int bx = blockIdx.x;
    if (bx < 5120) {
        __shared__ bf16 tile[32][33];
        const int z = bx >> 10;
        const int t = bx & 1023;
        const float* src = wp.p[z];
        bf16* d = wdst + (size_t)z * Dn * Dn;
        const int c0 = (t & 31) * 32, r0 = (t >> 5) * 32;
        const int tx = threadIdx.x & 31;
        const int ty = threadIdx.x >> 5;
#pragma unroll
        for (int dy = 0; dy < 32; dy += 8)
            tile[ty + dy][tx] = f2b(src[(size_t)(r0 + ty + dy) * Dn + (c0 + tx)]);
        __syncthreads();
#pragma unroll
        for (int dy = 0; dy < 32; dy += 8)
            d[(size_t)(c0 + ty + dy) * Dn + (r0 + tx)] = tile[tx][ty + dy];
    } else if (bx < 5128) {
        const int base = (bx - 5120) * 1024;
#pragma unroll
        for (int i = 0; i < 4; ++i) rowsum[base + i * 256 + threadIdx.x] = 0.0f;
    } else {
        const int row = bx - 5128;
        ln_row(x + (size_t)row * Dn, gamma1, beta1, h + (size_t)row * Dn, threadIdx.x);
    }
}

extern "C" void kernel_launch(void* const* d_in, const int* in_sizes, int n_in,
                              void* d_out, int out_size, void* d_ws, size_t ws_size,
                              hipStream_t stream) {
    const float* x      = (const float*)d_in[0];
    const float* gamma1 = (const float*)d_in[1];
    const float* beta1  = (const float*)d_in[2];
    const float* w_q    = (const float*)d_in[3];
    const float* w_k    = (const float*)d_in[4];
    const float* w_v    = (const float*)d_in[5];
    const float* gamma2 = (const float*)d_in[6];
    const float* beta2  = (const float*)d_in[7];
    const float* W1     = (const float*)d_in[8];
    const float* b1     = (const float*)d_in[9];
    const float* W2     = (const float*)d_in[10];
    const float* b2     = (const float*)d_in[11];
    float* out = (float*)d_out;   // fp32 output buffer (compared in bf16 space)

    char* ws = (char*)d_ws;
    size_t off = 0;
    auto alloc = [&](size_t bytes) {
        char* p = ws + off;
        off += (bytes + 255) & ~(size_t)255;
        return p;
    };
    const size_t BT = (size_t)Bn * Tn;
    bf16* h    = (bf16*)alloc(BT * Dn * 2);               // 16 MB; reused as h2
    bf16* qk   = (bf16*)alloc(BT * 2 * Dn * 2);           // 32 MB [8192,2048] (q|k)
    bf16* vt   = (bf16*)alloc(BT * Dn * 2);               // 16 MB [4][1024,2048]
    bf16* wbuf = (bf16*)alloc((size_t)5 * Dn * Dn * 2);   // 10 MB (wq|wk|wv|w1|w2)^T
    bf16* S    = (bf16*)alloc((size_t)Bn * Tn * Tn * 2);  // 32 MB masked exp scores
    bf16* y    = (bf16*)alloc(BT * Dn * 2);               // 16 MB
    float* rowsum = (float*)alloc((size_t)Bn * Tn * 4);   // 32 KB
    bf16* h2   = h;            // h dead after QKV
    bf16* mid  = qk;           // qk dead after scores

    const dim3 blk(256);
    const dim3 blk512(512);
    const long TD  = (long)Tn * Dn;
    const long TT  = (long)Tn * Tn;
    const long TD2 = (long)Tn * 2 * Dn;
    const size_t DD = (size_t)Dn * Dn;

    // fused: 5 weight transposes + rowsum zero + LN1
    WPtrs wp; wp.p[0] = w_q; wp.p[1] = w_k; wp.p[2] = w_v; wp.p[3] = W1; wp.p[4] = W2;
    prep_kernel<<<dim3(5128 + (unsigned)BT, 1, 1), blk, 0, stream>>>(
        wp, wbuf, rowsum, x, gamma1, beta1, h);

    // qk = h @ [wq|wk]^T : 8-phase 256^2, grid 32x8 = 256 blocks (1/CU)
    gemm8p<<<dim3(32, 8, 1), blk512, 0, stream>>>(
        h, wbuf, qk, Dn, Dn, Dn, 2 * Dn);

    // vt[b][d][t] = (h @ wv^T)^T : BK=64 pipeline + LDS-transpose epilogue
    gemm8k<1, 0, bf16, float, false><<<dim3(32, 8, 1), blk512, 0, stream>>>(
        h, wbuf + 2 * DD, (bf16*)nullptr, nullptr, nullptr, vt, nullptr,
        Dn, Dn, Dn, 0, 0, 0, 0, 0, 0);

    // S_exp = exp(q @ k^T * scale) causal-masked + atomic row sums
    gemm8k<2, 1, bf16, float, false><<<dim3(8, 16, Bn), blk512, 0, stream>>>(
        qk, qk + 1024, S, nullptr, nullptr, nullptr, rowsum,
        Dn, 2 * Dn, 2 * Dn, Tn, 0, TD2, TD2, TT, 0);

    // y = (S_exp @ V) / rowsum + x : K truncated at diagonal
    gemm8k<3, 2, bf16, float, false><<<dim3(8, 8, Bn), blk512, 0, stream>>>(
        S, vt, y, nullptr, x, nullptr, rowsum,
        Tn, Tn, Tn, Dn, Dn, TT, TD, TD, TD);

    // LN2: y (bf16) -> h2 (bf16)
    ln_kernel<bf16><<<dim3((unsigned)BT), blk, 0, stream>>>(y, gamma2, beta2, h2);

    // mid = relu(h2 @ W1 + b1)
    gemm8k<0, 0, bf16, float, true><<<dim3(32, 8, 1), blk512, 0, stream>>>(
        h2, wbuf + 3 * DD, mid, b1, nullptr, nullptr, nullptr,
        Dn, Dn, Dn, Dn, 0, 0, 0, 0, 0);

    // out = mid @ W2 + b2 + y (fp32 out, bf16 residual)
    gemm8k<0, 0, float, bf16, false><<<dim3(32, 8, 1), blk512, 0, stream>>>(
        mid, wbuf + 4 * DD, out, b2, y, nullptr, nullptr,
        Dn, Dn, Dn, Dn, Dn, 0, 0, 0, 0);
}

// Round 4
// 351.387 us; speedup vs baseline: 1.1153x; 1.1153x over previous
//
#include <hip/hip_runtime.h>
#include <hip/hip_bf16.h>
#include <math.h>

using bf16 = __hip_bfloat16;

static constexpr int Bn = 4;
static constexpr int Tn = 2048;
static constexpr int Dn = 1024;

typedef __attribute__((ext_vector_type(8))) short bf16x8;
typedef __attribute__((ext_vector_type(4))) float f32x4;

__device__ __forceinline__ float ldf(float v) { return v; }
__device__ __forceinline__ float ldf(bf16 v) { return __bfloat162float(v); }
__device__ __forceinline__ bf16 f2b(float v) { return __float2bfloat16(v); }
__device__ __forceinline__ float b2f(short s) {
    return __uint_as_float(((unsigned)(unsigned short)s) << 16);
}
__device__ __forceinline__ short f2bs(float v) {
    bf16 t = __float2bfloat16(v);
    return *reinterpret_cast<short*>(&t);
}

template <typename T> __device__ __forceinline__ T from_float(float v);
template <> __device__ __forceinline__ float from_float<float>(float v) { return v; }
template <> __device__ __forceinline__ bf16 from_float<bf16>(float v) { return f2b(v); }

__device__ __forceinline__ void load4(const float* p, float* v) {
    const float4 t = *(const float4*)p;
    v[0] = t.x; v[1] = t.y; v[2] = t.z; v[3] = t.w;
}
__device__ __forceinline__ void load4(const bf16* p, float* v) {
    const short4 t = *(const short4*)p;
    v[0] = b2f(t.x); v[1] = b2f(t.y); v[2] = b2f(t.z); v[3] = b2f(t.w);
}

// async global->LDS, 16B per lane; LDS dest wave-uniform base, HW scatters +lane*16.
__device__ __forceinline__ void async_copy16(const bf16* g, bf16* l) {
    __builtin_amdgcn_global_load_lds(
        (const __attribute__((address_space(1))) void*)g,
        (__attribute__((address_space(3))) void*)l,
        16, 0, 0);
}

// ---------------------------------------------------------------------------
// 8-phase-style 256xBN NT GEMM (bf16): C[m,n] = sum_k A[m,k]*B[n,k].
// T3+T4+T5 structure: raw s_barrier (NO vmcnt(0) drain in main loop), counted
// vmcnt once per K-tile, setprio(1) around MFMA clusters. BK=32, 3-deep ring.
// BN=256: 96 KiB LDS (2 blocks/CU possible), proven for QK.
// BN=128: 72 KiB LDS, used ONLY with EPI=1 (V-transpose) where it beat the
// alternatives in round 2. (Plain BN=128 MLPs regressed — do not use.)
// EPI 0: plain bf16 store; EPI 1 (BN=128): V-transpose into vtp[b][d][t].
// ---------------------------------------------------------------------------
template <int BN, int EPI, typename OutT, bool RELU>
__global__ __launch_bounds__(512, 2) void gemm8p(
    const bf16* __restrict__ A, const bf16* __restrict__ Bm,
    OutT* __restrict__ C, const float* __restrict__ bias,
    const bf16* __restrict__ res, bf16* __restrict__ vtp,
    int K, int lda, int ldb, int ldc)
{
    static_assert(EPI != 1 || BN == 128, "V-transpose epilogue needs BN=128");
    constexpr int BM = 256, BK = 32;
    constexpr int NT = BN / 64;                   // per-wave 16-col fragments
    constexpr int BUFE = (BM + BN) * BK;          // elems per buffer
    __shared__ __align__(16) bf16 smem[3 * BUFE];

    const int bm = blockIdx.x, bn = blockIdx.y;
    const int tid = threadIdx.x;
    const int wave = tid >> 6;
    const int lane = tid & 63;
    const int wm = wave >> 2;          // 0..1  (M direction, 128 rows each)
    const int wn = wave & 3;           // 0..3  (N direction, BN/4 cols each)
    const int lr = lane >> 2;          // staging: row within 16-row subtile
    const int lc = (lane & 3) * 8;     // staging: col (8 bf16 = 16B)
    const int arow = lane & 15;        // frag read: row within subtile
    const int kq = (lane >> 4) * 8;    // frag read: k-offset

    const int NK = K / BK;

    const bf16* gA0 = A + (size_t)(bm * BM + wave * 16 + lr) * lda + lc;
    const bf16* gA1 = A + (size_t)(bm * BM + (wave + 8) * 16 + lr) * lda + lc;
    const bf16* gB0 = Bm + (size_t)(bn * BN + wave * 16 + lr) * ldb + lc;
    const bf16* gB1 = (BN == 256)
        ? Bm + (size_t)(bn * BN + (wave + 8) * 16 + lr) * ldb + lc : nullptr;

    f32x4 acc[8][NT] = {};

    // ---- prologue: stage tiles 0 and 1, wait for tile 0 only ----
    {
        bf16* As0 = smem;               // buf 0
        bf16* Bs0 = smem + BM * BK;
        bf16* As1 = smem + BUFE;        // buf 1
        bf16* Bs1 = smem + BUFE + BM * BK;
        async_copy16(gA0, As0 + wave * 512);
        async_copy16(gA1, As0 + (wave + 8) * 512);
        async_copy16(gB0, Bs0 + wave * 512);
        if constexpr (BN == 256) async_copy16(gB1, Bs0 + (wave + 8) * 512);
        async_copy16(gA0 + BK, As1 + wave * 512);
        async_copy16(gA1 + BK, As1 + (wave + 8) * 512);
        async_copy16(gB0 + BK, Bs1 + wave * 512);
        if constexpr (BN == 256) async_copy16(gB1 + BK, Bs1 + (wave + 8) * 512);
    }
    if constexpr (BN == 256) asm volatile("s_waitcnt vmcnt(4)" ::: "memory");
    else                     asm volatile("s_waitcnt vmcnt(3)" ::: "memory");
    __builtin_amdgcn_s_barrier();

    int cb = 0;  // buffer holding current tile kt
    int sb = 2;  // buffer receiving tile kt+2
    for (int kt = 0; kt < NK; ++kt) {
        const bf16* As = smem + cb * BUFE;
        const bf16* Bs = As + BM * BK;
        const bool st = (kt + 2) < NK;
        const int koff = (kt + 2) * BK;

        // ============ phase 1: low half of N fragments ============
        bf16x8 af[8], bf0[NT / 2];
#pragma unroll
        for (int mt = 0; mt < 8; ++mt)
            af[mt] = *(const bf16x8*)&As[(wm * 8 + mt) * 512 + arow * 32 + kq];
#pragma unroll
        for (int nt = 0; nt < NT / 2; ++nt)
            bf0[nt] = *(const bf16x8*)&Bs[(wn * NT + nt) * 512 + arow * 32 + kq];
        if (st) {  // stage A half of tile kt+2
            bf16* Ad = smem + sb * BUFE;
            async_copy16(gA0 + koff, Ad + wave * 512);
            async_copy16(gA1 + koff, Ad + (wave + 8) * 512);
        }
        __builtin_amdgcn_s_barrier();
        asm volatile("s_waitcnt lgkmcnt(0)" ::: "memory");
        __builtin_amdgcn_sched_barrier(0);
        __builtin_amdgcn_s_setprio(1);
#pragma unroll
        for (int mt = 0; mt < 8; ++mt)
#pragma unroll
            for (int nt = 0; nt < NT / 2; ++nt)
                acc[mt][nt] = __builtin_amdgcn_mfma_f32_16x16x32_bf16(
                    af[mt], bf0[nt], acc[mt][nt], 0, 0, 0);
        __builtin_amdgcn_s_setprio(0);
        __builtin_amdgcn_s_barrier();

        // ============ phase 2: high half of N fragments ============
        bf16x8 bf1[NT / 2];
#pragma unroll
        for (int nt = 0; nt < NT / 2; ++nt)
            bf1[nt] = *(const bf16x8*)&Bs[(wn * NT + NT / 2 + nt) * 512 + arow * 32 + kq];
        if (st) {  // stage B half of tile kt+2
            bf16* Bd = smem + sb * BUFE + BM * BK;
            async_copy16(gB0 + koff, Bd + wave * 512);
            if constexpr (BN == 256) async_copy16(gB1 + koff, Bd + (wave + 8) * 512);
        }
        __builtin_amdgcn_s_barrier();
        asm volatile("s_waitcnt lgkmcnt(0)" ::: "memory");
        __builtin_amdgcn_sched_barrier(0);
        __builtin_amdgcn_s_setprio(1);
#pragma unroll
        for (int mt = 0; mt < 8; ++mt)
#pragma unroll
            for (int nt = 0; nt < NT / 2; ++nt)
                acc[mt][NT / 2 + nt] = __builtin_amdgcn_mfma_f32_16x16x32_bf16(
                    af[mt], bf1[nt], acc[mt][NT / 2 + nt], 0, 0, 0);
        __builtin_amdgcn_s_setprio(0);
        // counted wait: loads issued THIS tile (for kt+2) may stay in flight;
        // loads issued last tile (for kt+1) must have landed.
        if (st) {
            if constexpr (BN == 256) asm volatile("s_waitcnt vmcnt(4)" ::: "memory");
            else                     asm volatile("s_waitcnt vmcnt(3)" ::: "memory");
        } else {
            asm volatile("s_waitcnt vmcnt(0)" ::: "memory");
        }
        __builtin_amdgcn_s_barrier();

        cb = (cb + 1 == 3) ? 0 : cb + 1;
        sb = (sb + 1 == 3) ? 0 : sb + 1;
    }

    const int qrow = (lane >> 4) * 4;
    const int ccol = lane & 15;

    if constexpr (EPI == 1) {
        // V-transpose: block output is 256(t) x 128(d); write vt[b][d][t].
        // LDS buffer [128][264] bf16 = 67.6 KB fits in the 72 KB staging smem.
        bf16* tt = smem;
#pragma unroll
        for (int mt = 0; mt < 8; ++mt)
#pragma unroll
            for (int nt = 0; nt < NT; ++nt) {
                const int dl = wn * (NT * 16) + nt * 16 + ccol;
                const int tl = wm * 128 + mt * 16 + qrow;
                short4 o;
                o.x = f2bs(acc[mt][nt][0]);
                o.y = f2bs(acc[mt][nt][1]);
                o.z = f2bs(acc[mt][nt][2]);
                o.w = f2bs(acc[mt][nt][3]);
                *(short4*)&tt[dl * 264 + tl] = o;
            }
        __syncthreads();
        const int b = (bm * BM) >> 11;
        const int tin = (bm * BM) & (Tn - 1);
        const int dr = tid >> 4;           // 0..31
        const int t0 = (tid & 15) * 16;    // 0..240
#pragma unroll
        for (int p = 0; p < 4; ++p) {
            const int d = p * 32 + dr;
            const bf16* srcl = &tt[d * 264 + t0];
            bf16* dst = vtp + ((size_t)b * Dn + bn * BN + d) * Tn + tin + t0;
            ((bf16x8*)dst)[0] = ((const bf16x8*)srcl)[0];
            ((bf16x8*)dst)[1] = ((const bf16x8*)srcl)[1];
        }
        return;
    }

    // plain epilogue: +bias, optional RELU, optional bf16 residual
    const int row0 = bm * BM + wm * 128;
    const int col0 = bn * BN + wn * (NT * 16);
#pragma unroll
    for (int mt = 0; mt < 8; ++mt)
#pragma unroll
        for (int nt = 0; nt < NT; ++nt) {
            const int cc = col0 + nt * 16 + ccol;
            const float bv = bias ? bias[cc] : 0.0f;
#pragma unroll
            for (int r = 0; r < 4; ++r) {
                const int rr = row0 + mt * 16 + qrow + r;
                float v = acc[mt][nt][r] + bv;
                if (RELU) v = fmaxf(v, 0.0f);
                if (res) v += b2f(*(const short*)&res[(size_t)rr * ldc + cc]);
                C[(size_t)rr * ldc + cc] = from_float<OutT>(v);
            }
        }
}

// ---------------------------------------------------------------------------
// Generic NT GEMM (2-barrier 128x128 structure, 32 KiB LDS, 2-3 blocks/CU).
// Used for scores, PV, and the two MLP GEMMs.
// mode 0: plain full-K, grid (bm, bn, bz).
// mode 3: PV heavy-first — grid (bn, bz, bm'), bm = gridDim.z-1-blockIdx.z
//         (heavy blocks dispatch first), K truncated at bm*BM+BM.
// mode 4: scores heavy-first — same remap, causal block-skip, full K.
// EPI 0: plain (+bias/RELU/residual); 2: masked exp scores + atomic rowsum;
// EPI 3: divide by rowsum then + residual.
// ---------------------------------------------------------------------------
template <int BM, int BN, int MINW, int EPI, typename OutT, typename ResT, bool RELU>
__global__ __launch_bounds__(256, MINW) void gemm_nt(
    const bf16* __restrict__ A, const bf16* __restrict__ Bm,
    OutT* __restrict__ C, const float* __restrict__ bias,
    const ResT* __restrict__ res, float* __restrict__ rowsum,
    int M, int N, int K, int lda, int ldb, int ldc,
    long sA, long sB, long sC, long sR, int mode)
{
    int bm, bn, bz;
    if (mode >= 3) {
        bn = blockIdx.x; bz = blockIdx.y;
        bm = (int)gridDim.z - 1 - (int)blockIdx.z;   // heavy-first ordering
    } else {
        bm = blockIdx.x; bn = blockIdx.y; bz = blockIdx.z;
    }
    if (mode == 4 && bn * BN > bm * BM + (BM - 1)) return;
    const int kend = bm * BM + BM;
    const int kmax = (mode == 3) ? (kend < K ? kend : K) : K;

    const bf16* Ab = A + (size_t)bz * sA;
    const bf16* Bb = Bm + (size_t)bz * sB;

    constexpr int WROWS = BM / 64;
    constexpr int WCOLS = 4 / WROWS;
    constexpr int TM = 64;
    constexpr int TN = BN / WCOLS;
    constexpr int MT = TM / 16;
    constexpr int NT = TN / 16;
    constexpr int nA = BM / 16;
    constexpr int nB = BN / 16;
    constexpr int STAGE = 2 * (BM + BN) * 32;

    __shared__ __align__(16) bf16 smem[STAGE];
    bf16* As = smem;
    bf16* Bs = smem + 2 * BM * 32;

    const int tid = threadIdx.x;
    const int wave = tid >> 6;
    const int lane = tid & 63;
    const int wm = wave / WCOLS;
    const int wn = wave % WCOLS;

    f32x4 acc[MT][NT] = {};

    const int lr = lane >> 2;
    const int lc = (lane & 3) * 8;
    const bf16* gAc[nA / 4]; bf16* lAc[nA / 4];
    const bf16* gBc[nB / 4]; bf16* lBc[nB / 4];
#pragma unroll
    for (int i = 0; i < nA / 4; ++i) {
        const int c = wave + 4 * i;
        gAc[i] = Ab + (size_t)(bm * BM + c * 16 + lr) * lda + lc;
        lAc[i] = &As[c * 512];
    }
#pragma unroll
    for (int i = 0; i < nB / 4; ++i) {
        const int c = wave + 4 * i;
        gBc[i] = Bb + (size_t)(bn * BN + c * 16 + lr) * ldb + lc;
        lBc[i] = &Bs[c * 512];
    }

    const int arow = lane & 15;
    const int kq = (lane >> 4) * 8;

    for (int k0 = 0; k0 < kmax; k0 += 64) {
#pragma unroll
        for (int hh = 0; hh < 2; ++hh) {
#pragma unroll
            for (int i = 0; i < nA / 4; ++i)
                async_copy16(gAc[i] + k0 + 32 * hh, lAc[i] + hh * (BM * 32));
#pragma unroll
            for (int i = 0; i < nB / 4; ++i)
                async_copy16(gBc[i] + k0 + 32 * hh, lBc[i] + hh * (BN * 32));
        }
        __syncthreads();

#pragma unroll
        for (int hh = 0; hh < 2; ++hh) {
            const bf16* Ah = As + hh * (BM * 32);
            const bf16* Bh = Bs + hh * (BN * 32);
            bf16x8 af[MT], bfm[NT];
#pragma unroll
            for (int t = 0; t < MT; ++t)
                af[t] = *(const bf16x8*)&Ah[(wm * TM + t * 16 + arow) * 32 + kq];
#pragma unroll
            for (int t = 0; t < NT; ++t)
                bfm[t] = *(const bf16x8*)&Bh[(wn * TN + t * 16 + arow) * 32 + kq];
#pragma unroll
            for (int mt = 0; mt < MT; ++mt)
#pragma unroll
                for (int nt = 0; nt < NT; ++nt)
                    acc[mt][nt] = __builtin_amdgcn_mfma_f32_16x16x32_bf16(
                        af[mt], bfm[nt], acc[mt][nt], 0, 0, 0);
        }
        __syncthreads();
    }

    const int rowBase = bm * BM + wm * TM;
    const int colBase = bn * BN + wn * TN;
    const int qrow = (lane >> 4) * 4;
    const int ccol = lane & 15;

    if (EPI == 2) {
        // masked exp scores + atomic row sums (of the bf16-rounded values)
        OutT* Cb = C + (size_t)bz * sC;
        float* rsb = rowsum + (size_t)bz * Tn;
        const float scale = 0.03125f;
#pragma unroll
        for (int mt = 0; mt < MT; ++mt) {
            float rsv[4] = {0.f, 0.f, 0.f, 0.f};
#pragma unroll
            for (int nt = 0; nt < NT; ++nt) {
                const int cc = colBase + nt * 16 + ccol;
#pragma unroll
                for (int r = 0; r < 4; ++r) {
                    const int rr = rowBase + mt * 16 + qrow + r;
                    float e = 0.0f;
                    if (cc <= rr) {
                        const short es = f2bs(__expf(acc[mt][nt][r] * scale));
                        Cb[(size_t)rr * ldc + cc] = *(const bf16*)&es;
                        e = b2f(es);
                    } else {
                        Cb[(size_t)rr * ldc + cc] = from_float<OutT>(0.0f);
                    }
                    rsv[r] += e;
                }
            }
#pragma unroll
            for (int r = 0; r < 4; ++r) {
                float v = rsv[r];
                v += __shfl_xor(v, 1);
                v += __shfl_xor(v, 2);
                v += __shfl_xor(v, 4);
                v += __shfl_xor(v, 8);
                if (ccol == 0)
                    atomicAdd(rsb + rowBase + mt * 16 + qrow + r, v);
            }
        }
        return;
    }

    OutT* Cb = C + (size_t)bz * sC;
    const ResT* Rb = res ? (res + (size_t)bz * sR) : nullptr;
    const float* rsb = (EPI == 3) ? (rowsum + (size_t)bz * Tn) : nullptr;
#pragma unroll
    for (int mt = 0; mt < MT; ++mt) {
        float inv4[4];
        if (EPI == 3) {
#pragma unroll
            for (int r = 0; r < 4; ++r)
                inv4[r] = 1.0f / rsb[rowBase + mt * 16 + qrow + r];
        }
#pragma unroll
        for (int nt = 0; nt < NT; ++nt) {
            const int cc = colBase + nt * 16 + ccol;
            const float bv = bias ? bias[cc] : 0.0f;
#pragma unroll
            for (int r = 0; r < 4; ++r) {
                const int rr = rowBase + mt * 16 + qrow + r;
                float v = acc[mt][nt][r];
                if (EPI == 3) v *= inv4[r];
                v += bv;
                if (RELU) v = fmaxf(v, 0.0f);
                if (Rb) v += ldf(Rb[(size_t)rr * ldc + cc]);
                Cb[(size_t)rr * ldc + cc] = from_float<OutT>(v);
            }
        }
    }
}

// ---------------------------------------------------------------------------
// LayerNorm body (faithfully buggy): out = (x - mean/sqrt(var_unbiased))*g + b
// ---------------------------------------------------------------------------
template <typename InT>
__device__ __forceinline__ void ln_row(
    const InT* __restrict__ xr, const float* __restrict__ gamma,
    const float* __restrict__ beta, bf16* __restrict__ orow, int tid)
{
    const int j = tid * 4;
    float v[4];
    load4(xr + j, v);
    float s = v[0] + v[1] + v[2] + v[3];
    float sq = v[0] * v[0] + v[1] * v[1] + v[2] * v[2] + v[3] * v[3];
#pragma unroll
    for (int o = 32; o > 0; o >>= 1) {
        s += __shfl_down(s, o);
        sq += __shfl_down(sq, o);
    }
    __shared__ float red[2][4];
    const int lane = tid & 63, w = tid >> 6;
    if (lane == 0) { red[0][w] = s; red[1][w] = sq; }
    __syncthreads();
    s  = red[0][0] + red[0][1] + red[0][2] + red[0][3];
    sq = red[1][0] + red[1][1] + red[1][2] + red[1][3];
    const float mean = s / (float)Dn;
    const float var = (sq - s * s / (float)Dn) / (float)(Dn - 1);
    const float coef = mean * rsqrtf(var);

    const float4 g = *(const float4*)(gamma + j);
    const float4 be = *(const float4*)(beta + j);
    short4 o;
    o.x = f2bs((v[0] - coef) * g.x + be.x);
    o.y = f2bs((v[1] - coef) * g.y + be.y);
    o.z = f2bs((v[2] - coef) * g.z + be.z);
    o.w = f2bs((v[3] - coef) * g.w + be.w);
    *(short4*)(orow + j) = o;
}

template <typename InT>
__global__ __launch_bounds__(256) void ln_kernel(
    const InT* __restrict__ x, const float* __restrict__ gamma,
    const float* __restrict__ beta, bf16* __restrict__ out)
{
    const int row = blockIdx.x;
    ln_row(x + (size_t)row * Dn, gamma, beta, out + (size_t)row * Dn, threadIdx.x);
}

// ---------------------------------------------------------------------------
// Fused prep: [0,5120) weight transposes (5 x 1024^2, fp32->bf16),
// [5120,5128) zero rowsum, [5128,13320) LN1 rows.
// ---------------------------------------------------------------------------
struct WPtrs { const float* p[5]; };

__global__ __launch_bounds__(256) void prep_kernel(
    WPtrs wp, bf16* __restrict__ wdst, float* __restrict__ rowsum,
    const float* __restrict__ x, const float* __restrict__ gamma1,
    const float* __restrict__ beta1, bf16* __restrict__ h)
{
    const int bx = blockIdx.x;
    if (bx < 5120) {
        __shared__ bf16 tile[32][33];
        const int z = bx >> 10;
        const int t = bx & 1023;
        const float* src = wp.p[z];
        bf16* d = wdst + (size_t)z * Dn * Dn;
        const int c0 = (t & 31) * 32, r0 = (t >> 5) * 32;
        const int tx = threadIdx.x & 31;
        const int ty = threadIdx.x >> 5;
#pragma unroll
        for (int dy = 0; dy < 32; dy += 8)
            tile[ty + dy][tx] = f2b(src[(size_t)(r0 + ty + dy) * Dn + (c0 + tx)]);
        __syncthreads();
#pragma unroll
        for (int dy = 0; dy < 32; dy += 8)
            d[(size_t)(c0 + ty + dy) * Dn + (r0 + tx)] = tile[tx][ty + dy];
    } else if (bx < 5128) {
        const int base = (bx - 5120) * 1024;
#pragma unroll
        for (int i = 0; i < 4; ++i) rowsum[base + i * 256 + threadIdx.x] = 0.0f;
    } else {
        const int row = bx - 5128;
        ln_row(x + (size_t)row * Dn, gamma1, beta1, h + (size_t)row * Dn, threadIdx.x);
    }
}

extern "C" void kernel_launch(void* const* d_in, const int* in_sizes, int n_in,
                              void* d_out, int out_size, void* d_ws, size_t ws_size,
                              hipStream_t stream) {
    const float* x      = (const float*)d_in[0];
    const float* gamma1 = (const float*)d_in[1];
    const float* beta1  = (const float*)d_in[2];
    const float* w_q    = (const float*)d_in[3];
    const float* w_k    = (const float*)d_in[4];
    const float* w_v    = (const float*)d_in[5];
    const float* gamma2 = (const float*)d_in[6];
    const float* beta2  = (const float*)d_in[7];
    const float* W1     = (const float*)d_in[8];
    const float* b1     = (const float*)d_in[9];
    const float* W2     = (const float*)d_in[10];
    const float* b2     = (const float*)d_in[11];
    float* out = (float*)d_out;   // fp32 output buffer (compared in bf16 space)

    char* ws = (char*)d_ws;
    size_t off = 0;
    auto alloc = [&](size_t bytes) {
        char* p = ws + off;
        off += (bytes + 255) & ~(size_t)255;
        return p;
    };
    const size_t BT = (size_t)Bn * Tn;
    bf16* h    = (bf16*)alloc(BT * Dn * 2);               // 16 MB; reused as h2
    bf16* qk   = (bf16*)alloc(BT * 2 * Dn * 2);           // 32 MB [8192,2048] (q|k)
    bf16* vt   = (bf16*)alloc(BT * Dn * 2);               // 16 MB [4][1024,2048]
    bf16* wbuf = (bf16*)alloc((size_t)5 * Dn * Dn * 2);   // 10 MB (wq|wk|wv|w1|w2)^T
    bf16* S    = (bf16*)alloc((size_t)Bn * Tn * Tn * 2);  // 32 MB masked exp scores
    bf16* y    = (bf16*)alloc(BT * Dn * 2);               // 16 MB
    float* rowsum = (float*)alloc((size_t)Bn * Tn * 4);   // 32 KB
    bf16* h2   = h;            // h dead after QKV
    bf16* mid  = qk;           // qk dead after scores

    const dim3 blk(256);
    const dim3 blk512(512);
    const long TD  = (long)Tn * Dn;
    const long TT  = (long)Tn * Tn;
    const long TD2 = (long)Tn * 2 * Dn;
    const size_t DD = (size_t)Dn * Dn;

    // fused: 5 weight transposes + rowsum zero + LN1
    WPtrs wp; wp.p[0] = w_q; wp.p[1] = w_k; wp.p[2] = w_v; wp.p[3] = W1; wp.p[4] = W2;
    prep_kernel<<<dim3(5128 + (unsigned)BT, 1, 1), blk, 0, stream>>>(
        wp, wbuf, rowsum, x, gamma1, beta1, h);

    // qk = h @ [wq|wk]^T : 8-phase 256^2, grid 32x8 = 256 blocks (1/CU)
    gemm8p<256, 0, bf16, false><<<dim3(32, 8, 1), blk512, 0, stream>>>(
        h, wbuf, qk, nullptr, nullptr, nullptr, Dn, Dn, Dn, 2 * Dn);

    // vt[b][d][t] = (h @ wv^T)^T : 8-phase 256x128 + LDS-transpose epilogue
    gemm8p<128, 1, bf16, false><<<dim3(32, 8, 1), blk512, 0, stream>>>(
        h, wbuf + 2 * DD, (bf16*)nullptr, nullptr, nullptr, vt,
        Dn, Dn, Dn, 0);

    // S_exp = exp(q @ k^T * scale) causal-masked + atomic row sums
    // heavy-first: bm on slowest grid dim, reversed (mode 4)
    gemm_nt<128, 128, 4, 2, bf16, float, false><<<dim3(16, Bn, 16), blk, 0, stream>>>(
        qk, qk + 1024, S, nullptr, nullptr, rowsum,
        Tn, Tn, Dn, 2 * Dn, 2 * Dn, Tn, TD2, TD2, TT, 0, 4);

    // y = (S_exp @ V) / rowsum + x : K truncated at diagonal, heavy-first (mode 3)
    gemm_nt<128, 128, 4, 3, bf16, float, false><<<dim3(8, Bn, 16), blk, 0, stream>>>(
        S, vt, y, nullptr, x, rowsum,
        Tn, Dn, Tn, Tn, Tn, Dn, TT, TD, TD, TD, 3);

    // LN2: y (bf16) -> h2 (bf16)
    ln_kernel<bf16><<<dim3((unsigned)BT), blk, 0, stream>>>(y, gamma2, beta2, h2);

    // mid = relu(h2 @ W1 + b1)
    gemm_nt<128, 128, 4, 0, bf16, float, true><<<dim3(64, 8, 1), blk, 0, stream>>>(
        h2, wbuf + 3 * DD, mid, b1, nullptr, nullptr,
        (int)BT, Dn, Dn, Dn, Dn, Dn, 0, 0, 0, 0, 0);

    // out = mid @ W2 + b2 + y (fp32 out, bf16 residual)
    gemm_nt<128, 128, 4, 0, float, bf16, false><<<dim3(64, 8, 1), blk, 0, stream>>>(
        mid, wbuf + 4 * DD, out, b2, y, nullptr,
        (int)BT, Dn, Dn, Dn, Dn, Dn, 0, 0, 0, 0, 0);
}